// Round 8
// baseline (200.339 us; speedup 1.0000x reference)
//
#include <hip/hip_runtime.h>

#define N_NODES 100000
#define N_EDGES 3200000
#define NVEC    (N_EDGES / 4)           // 800000 int4 per stream

#define S_LOG2  10
#define S       (1 << S_LOG2)           // 1024 nodes per partition
#define NPART   ((N_NODES + S - 1) / S) // 98 partitions
#define NC      8                       // chunks per partition -> 784 blocks
#define QW      512                     // scan-path per-wave queue entries

#define EPB     8192                    // edges per pass-A block
#define NB      ((N_EDGES + EPB - 1) / EPB)   // 391
#define CAP     35000                   // bucket capacity (mean 32653, ~13 sigma)

constexpr float DSIGMA_DT  = -0.0001f;
constexpr float PHI_THRESH = 0.3f;
constexpr float EPS        = 1e-8f;

// posT[i] = (pos.x, pos.y, pos.z, T) — one 16B gather per endpoint.
__global__ void prep_kernel(const float* __restrict__ x,
                            const float* __restrict__ pos,
                            float4* __restrict__ posT) {
    int i = blockIdx.x * blockDim.x + threadIdx.x;
    if (i < N_NODES)
        posT[i] = make_float4(pos[3 * i], pos[3 * i + 1], pos[3 * i + 2],
                              x[9 * i + 3]);
}

// ---------------- Pass A: counting-sort edges into 98 partition buckets ----
__global__ __launch_bounds__(512) void bin_kernel(const int4* __restrict__ ei4,
                                                  int* __restrict__ gcur,
                                                  int* __restrict__ buckets) {
    __shared__ int lbuf[EPB];                 // 32 KB locally sorted entries
    __shared__ int hist[NPART], lofs[NPART], cur[NPART], baseg[NPART];
    const int tid = threadIdx.x;
    const int ebase = blockIdx.x * EPB;
    const int n = min(EPB, N_EDGES - ebase);  // multiple of 4
    const int nv = n >> 2;
    const int4* __restrict__ src4 = ei4 + (ebase >> 2);
    const int4* __restrict__ dst4 = ei4 + NVEC + (ebase >> 2);

    if (tid < NPART) hist[tid] = 0;
    __syncthreads();

    for (int v = tid; v < nv; v += 512) {
        int4 d = dst4[v];
        atomicAdd(&hist[d.x >> S_LOG2], 1);
        atomicAdd(&hist[d.y >> S_LOG2], 1);
        atomicAdd(&hist[d.z >> S_LOG2], 1);
        atomicAdd(&hist[d.w >> S_LOG2], 1);
    }
    __syncthreads();

    if (tid == 0) {
        int run = 0;
        for (int b = 0; b < NPART; ++b) { lofs[b] = run; cur[b] = run; run += hist[b]; }
    }
    if (tid < NPART) baseg[tid] = atomicAdd(&gcur[tid], hist[tid]);
    __syncthreads();

    for (int v = tid; v < nv; v += 512) {
        int4 s = src4[v];
        int4 d = dst4[v];
#pragma unroll
        for (int k = 0; k < 4; ++k) {
            int dk = k == 0 ? d.x : k == 1 ? d.y : k == 2 ? d.z : d.w;
            int sk = k == 0 ? s.x : k == 1 ? s.y : k == 2 ? s.z : s.w;
            int bin = dk >> S_LOG2;
            int pk  = (sk << S_LOG2) | (dk & (S - 1));
            int off = atomicAdd(&cur[bin], 1);
            lbuf[off] = pk;
        }
    }
    __syncthreads();

    // coalesced per-bin copy-out to reserved global runs
    for (int b = 0; b < NPART; ++b) {
        int cnt = hist[b], lb = lofs[b], gb = baseg[b];
        int* __restrict__ dp = buckets + (size_t)b * CAP + gb;
        for (int i = tid; i < cnt; i += 512)
            if (gb + i < CAP) dp[i] = lbuf[lb + i];
    }
}

// ---------------- Pass B: dense per-partition accumulation -----------------
// B-side posT window staged in LDS (16 KB) -> only ONE divergent global
// lane-request per edge (the A-side gather). accum SoA 16 KB. 32 KB total.
__global__ __launch_bounds__(512, 8) void part_kernel(
        const int* __restrict__ gcur,
        const int* __restrict__ buckets,
        const float4* __restrict__ posT,
        float4* __restrict__ partials) {
    __shared__ float accx[S], accy[S], accz[S], accw[S];  // 16 KB SoA
    __shared__ float4 lposT[S];                            // 16 KB window
    const int c = blockIdx.x, p = blockIdx.y, tid = threadIdx.x;
    const int lo = p << S_LOG2;

    for (int i = tid; i < S; i += 512) {
        accx[i] = 0.f; accy[i] = 0.f; accz[i] = 0.f; accw[i] = 0.f;
        lposT[i] = (lo + i < N_NODES) ? posT[lo + i]
                                      : make_float4(0.f, 0.f, 0.f, 0.f);
    }
    __syncthreads();

    const int len = min(gcur[p], CAP);
    // 4-aligned chunk boundaries
    const int beg = (int)((long long)len * c / NC) & ~3;
    const int end = (c == NC - 1) ? (len & ~3)
                                  : ((int)((long long)len * (c + 1) / NC) & ~3);
    const int* __restrict__ bp = buckets + (size_t)p * CAP;

    // 4 edges per thread-iteration: 1 int4 index load -> 4 global gathers.
    const int ng = (end - beg) >> 2;
    for (int g = tid; g < ng; g += 512) {
        int4 pa = *(const int4*)(bp + beg + (g << 2));   // 16B-aligned
        int pk[4] = {pa.x, pa.y, pa.z, pa.w};
        float4 av[4];
#pragma unroll
        for (int k = 0; k < 4; ++k)
            av[k] = posT[pk[k] >> S_LOG2];               // A-side: global gather
#pragma unroll
        for (int k = 0; k < 4; ++k) {
            int r_ = pk[k] & (S - 1);
            float4 b = lposT[r_];                        // B-side: LDS
            float px = av[k].x - b.x;
            float py = av[k].y - b.y;
            float pz = av[k].z - b.z;
            float dT = av[k].w - b.w;
            float w  = dT / (px * px + py * py + pz * pz + EPS);
            atomicAdd(&accx[r_], w * px);
            atomicAdd(&accy[r_], w * py);
            atomicAdd(&accz[r_], w * pz);
            atomicAdd(&accw[r_], 1.0f);
        }
    }
    // tail (<4 entries), last chunk only
    if (c == NC - 1) {
        for (int i = (len & ~3) + tid; i < len; i += 512) {
            int pk1 = bp[i];
            int r_ = pk1 & (S - 1);
            float4 a = posT[pk1 >> S_LOG2];
            float4 b = lposT[r_];
            float px = a.x - b.x, py = a.y - b.y, pz = a.z - b.z;
            float dT = a.w - b.w;
            float w  = dT / (px * px + py * py + pz * pz + EPS);
            atomicAdd(&accx[r_], w * px);
            atomicAdd(&accy[r_], w * py);
            atomicAdd(&accz[r_], w * pz);
            atomicAdd(&accw[r_], 1.0f);
        }
    }
    __syncthreads();

    float4* __restrict__ outp = partials + ((size_t)(p * NC + c) << S_LOG2);
    for (int i = tid; i < S; i += 512)
        outp[i] = make_float4(accx[i], accy[i], accz[i], accw[i]);
}

// Sum the NC partials per node, apply mask * DSIGMA_DT / max(cnt,1).
__global__ void finalize_kernel(const float* __restrict__ x,
                                const float4* __restrict__ partials,
                                float* __restrict__ out) {
    int i = blockIdx.x * blockDim.x + threadIdx.x;
    if (i >= N_NODES) return;
    int p = i >> S_LOG2;
    int s = i & (S - 1);
    float ax = 0.f, ay = 0.f, az = 0.f, aw = 0.f;
#pragma unroll
    for (int c = 0; c < NC; ++c) {
        float4 t = partials[(((size_t)(p * NC + c)) << S_LOG2) + s];
        ax += t.x; ay += t.y; az += t.z; aw += t.w;
    }
    float phi = x[i * 9 + 8];
    float cn = aw > 1.0f ? aw : 1.0f;
    float m = (fabsf(phi) < PHI_THRESH) ? (DSIGMA_DT / cn) : 0.0f;
    out[3 * i]     = m * ax;
    out[3 * i + 1] = m * ay;
    out[3 * i + 2] = m * az;
}

// ---------------- mid fallback: scan+queue path ---------------------------
__global__ __launch_bounds__(256) void mp_scatter_kernel(
        const int4* __restrict__ ei4,
        const float4* __restrict__ posT,
        float4* __restrict__ partials) {
    __shared__ float accx[S], accy[S], accz[S], accw[S];
    __shared__ int   queue[4 * QW];

    const int c    = blockIdx.x;
    const int p    = blockIdx.y;
    const int lo   = p << S_LOG2;
    const int tid  = threadIdx.x;
    const int lane = tid & 63;
    const int wid  = tid >> 6;
    int* const q   = queue + wid * QW;

    for (int i = tid; i < S; i += 256) {
        accx[i] = 0.f; accy[i] = 0.f; accz[i] = 0.f; accw[i] = 0.f;
    }
    __syncthreads();

    const int4* __restrict__ src4 = ei4;
    const int4* __restrict__ dst4 = ei4 + NVEC;
    const int VPC = NVEC / NC;
    const int vbase = c * VPC;
    const int vend  = vbase + VPC;
    const int niter = (VPC + 255) / 256;
    int qcnt = 0;

    auto drain = [&]() {
        for (int i = lane; i < qcnt; i += 64) {
            int pk = q[i];
            int s_ = pk >> S_LOG2;
            int r_ = pk & (S - 1);
            float4 a = posT[s_];
            float4 b = posT[lo + r_];
            float px = a.x - b.x, py = a.y - b.y, pz = a.z - b.z;
            float dT = a.w - b.w;
            float w  = dT / (px * px + py * py + pz * pz + EPS);
            atomicAdd(&accx[r_], w * px);
            atomicAdd(&accy[r_], w * py);
            atomicAdd(&accz[r_], w * pz);
            atomicAdd(&accw[r_], 1.0f);
        }
        qcnt = 0;
    };

    for (int it = 0; it < niter; ++it) {
        int v = vbase + it * 256 + tid;
        bool valid = v < vend;
        int4 d = valid ? dst4[v] : make_int4(-1, -1, -1, -1);
        int4 s = valid ? src4[v] : make_int4(0, 0, 0, 0);
#pragma unroll
        for (int k = 0; k < 4; ++k) {
            int dk = k == 0 ? d.x : k == 1 ? d.y : k == 2 ? d.z : d.w;
            int sk = k == 0 ? s.x : k == 1 ? s.y : k == 2 ? s.z : s.w;
            unsigned r = (unsigned)(dk - lo);
            bool pred = (r < S);
            unsigned long long m = __ballot(pred);
            int rank = __popcll(m & ((1ull << lane) - 1ull));
            if (pred) q[qcnt + rank] = (sk << S_LOG2) | (int)r;
            qcnt += (int)__popcll(m);
        }
        if (qcnt >= QW - 256) drain();
    }
    drain();
    __syncthreads();

    float4* __restrict__ outp = partials + ((size_t)(p * NC + c) << S_LOG2);
    for (int i = tid; i < S; i += 256)
        outp[i] = make_float4(accx[i], accy[i], accz[i], accw[i]);
}

// ---------------- last fallback: global atomics ---------------------------
__global__ void edge_scatter_atomic_kernel(const int* __restrict__ ei,
                                           const float4* __restrict__ posT,
                                           float4* __restrict__ accum) {
    int e = blockIdx.x * blockDim.x + threadIdx.x;
    if (e >= N_EDGES) return;
    int s = ei[e];
    int d = ei[N_EDGES + e];
    float4 a = posT[s];
    float4 b = posT[d];
    float px = a.x - b.x, py = a.y - b.y, pz = a.z - b.z;
    float dT = a.w - b.w;
    float w  = dT / (px * px + py * py + pz * pz + EPS);
    float* ac = (float*)&accum[d];
    atomicAdd(ac,     w * px);
    atomicAdd(ac + 1, w * py);
    atomicAdd(ac + 2, w * pz);
    atomicAdd(ac + 3, 1.0f);
}

__global__ void finalize_accum_kernel(const float* __restrict__ x,
                                      const float4* __restrict__ accum,
                                      float* __restrict__ out) {
    int i = blockIdx.x * blockDim.x + threadIdx.x;
    if (i >= N_NODES) return;
    float4 a = accum[i];
    float phi = x[i * 9 + 8];
    float cn = a.w > 1.0f ? a.w : 1.0f;
    float m = (fabsf(phi) < PHI_THRESH) ? (DSIGMA_DT / cn) : 0.0f;
    out[3 * i]     = m * a.x;
    out[3 * i + 1] = m * a.y;
    out[3 * i + 2] = m * a.z;
}

extern "C" void kernel_launch(void* const* d_in, const int* in_sizes, int n_in,
                              void* d_out, int out_size, void* d_ws, size_t ws_size,
                              hipStream_t stream) {
    const float* x   = (const float*)d_in[0];
    const float* pos = (const float*)d_in[1];
    const int*   ei  = (const int*)d_in[2];
    float* out = (float*)d_out;

    // ws layout: [posT][partials][gcur pad 512B][buckets]
    const size_t posT_b = (size_t)N_NODES * sizeof(float4);          // 1.6 MB
    const size_t part_b = (size_t)NC * NPART * S * sizeof(float4);   // 12.8 MB
    const size_t gcur_b = 512;
    const size_t buck_b = (size_t)NPART * CAP * sizeof(int);         // 13.7 MB

    char* w = (char*)d_ws;
    float4* posT     = (float4*)w;
    float4* partials = (float4*)(w + posT_b);
    int*    gcur     = (int*)(w + posT_b + part_b);
    int*    buckets  = (int*)(w + posT_b + part_b + gcur_b);

    const size_t need_full = posT_b + part_b + gcur_b + buck_b;      // ~28.2 MB
    const size_t need_scan = posT_b + part_b;

    const int B = 256;
    prep_kernel<<<(N_NODES + B - 1) / B, B, 0, stream>>>(x, pos, posT);

    if (ws_size >= need_full) {
        hipMemsetAsync(gcur, 0, gcur_b, stream);
        bin_kernel<<<NB, 512, 0, stream>>>((const int4*)ei, gcur, buckets);
        dim3 grid(NC, NPART);
        part_kernel<<<grid, 512, 0, stream>>>(gcur, buckets, posT, partials);
        finalize_kernel<<<(N_NODES + B - 1) / B, B, 0, stream>>>(x, partials, out);
    } else if (ws_size >= need_scan) {
        dim3 grid(NC, NPART);
        mp_scatter_kernel<<<grid, B, 0, stream>>>((const int4*)ei, posT, partials);
        finalize_kernel<<<(N_NODES + B - 1) / B, B, 0, stream>>>(x, partials, out);
    } else {
        float4* accum = (float4*)(w + posT_b);  // 1.6 MB
        hipMemsetAsync(accum, 0, (size_t)N_NODES * sizeof(float4), stream);
        edge_scatter_atomic_kernel<<<(N_EDGES + B - 1) / B, B, 0, stream>>>(ei, posT, accum);
        finalize_accum_kernel<<<(N_NODES + B - 1) / B, B, 0, stream>>>(x, accum, out);
    }
}

// Round 10
// 140.544 us; speedup vs baseline: 1.4254x; 1.4254x over previous
//
#include <hip/hip_runtime.h>

#define N_NODES 100000
#define N_EDGES 3200000
#define NVEC    (N_EDGES / 4)           // 800000 int4 per stream

#define S_LOG2  10
#define S       (1 << S_LOG2)           // 1024 nodes per partition
#define NPART   ((N_NODES + S - 1) / S) // 98 partitions
#define NC      8                       // chunks per partition -> 784 blocks
#define QW      512                     // scan-path per-wave queue entries
#define EMAX    4376                    // max entries per chunk (ceil(CAP/NC)+1)

#define EPB     8192                    // edges per pass-A block
#define NB      ((N_EDGES + EPB - 1) / EPB)   // 391
#define CAP     35000                   // bucket capacity (mean 32653, ~13 sigma)

constexpr float DSIGMA_DT  = -0.0001f;
constexpr float PHI_THRESH = 0.3f;
constexpr float EPS        = 1e-8f;

// ---------------- Pass A: counting-sort edges into 98 partition buckets ----
// (prep fused: each block also packs a 256-node slice of posT)
__global__ __launch_bounds__(512) void bin_kernel(const int4* __restrict__ ei4,
                                                  const float* __restrict__ x,
                                                  const float* __restrict__ pos,
                                                  float4* __restrict__ posT,
                                                  int* __restrict__ gcur,
                                                  int* __restrict__ buckets) {
    __shared__ int lbuf[EPB];                 // 32 KB locally sorted entries
    __shared__ int hist[NPART], lofs[NPART], cur[NPART], baseg[NPART];
    const int tid = threadIdx.x;

    // fused prep: slice of posT
    {
        const int per = (N_NODES + NB - 1) / NB;   // 256
        const int lo = blockIdx.x * per;
        const int hi = min(lo + per, N_NODES);
        for (int i = lo + tid; i < hi; i += 512)
            posT[i] = make_float4(pos[3 * i], pos[3 * i + 1], pos[3 * i + 2],
                                  x[9 * i + 3]);
    }

    const int ebase = blockIdx.x * EPB;
    const int n = min(EPB, N_EDGES - ebase);  // multiple of 4
    const int nv = n >> 2;
    const int4* __restrict__ src4 = ei4 + (ebase >> 2);
    const int4* __restrict__ dst4 = ei4 + NVEC + (ebase >> 2);

    if (tid < NPART) hist[tid] = 0;
    __syncthreads();

    for (int v = tid; v < nv; v += 512) {
        int4 d = dst4[v];
        atomicAdd(&hist[d.x >> S_LOG2], 1);
        atomicAdd(&hist[d.y >> S_LOG2], 1);
        atomicAdd(&hist[d.z >> S_LOG2], 1);
        atomicAdd(&hist[d.w >> S_LOG2], 1);
    }
    __syncthreads();

    if (tid == 0) {
        int run = 0;
        for (int b = 0; b < NPART; ++b) { lofs[b] = run; cur[b] = run; run += hist[b]; }
    }
    if (tid < NPART) baseg[tid] = atomicAdd(&gcur[tid], hist[tid]);
    __syncthreads();

    for (int v = tid; v < nv; v += 512) {
        int4 s = src4[v];
        int4 d = dst4[v];
#pragma unroll
        for (int k = 0; k < 4; ++k) {
            int dk = k == 0 ? d.x : k == 1 ? d.y : k == 2 ? d.z : d.w;
            int sk = k == 0 ? s.x : k == 1 ? s.y : k == 2 ? s.z : s.w;
            int bin = dk >> S_LOG2;
            int pk  = (sk << S_LOG2) | (dk & (S - 1));
            int off = atomicAdd(&cur[bin], 1);
            lbuf[off] = pk;
        }
    }
    __syncthreads();

    // coalesced per-bin copy-out to reserved global runs
    for (int b = 0; b < NPART; ++b) {
        int cnt = hist[b], lb = lofs[b], gb = baseg[b];
        int* __restrict__ dp = buckets + (size_t)b * CAP + gb;
        for (int i = tid; i < cnt; i += 512)
            if (gb + i < CAP) dp[i] = lbuf[lb + i];
    }
}

// ---------------- Pass B: in-LDS counting sort + atomic-free reduce --------
// Per chunk: stage entries -> per-node histogram (1 int atomic/edge) ->
// prefix scan -> dst-sorted scatter (1 rtn int atomic/edge) -> each thread
// reduces contiguous per-node segments in REGISTERS (0 atomics). cnt = hist.
__global__ __launch_bounds__(512) void part_kernel(
        const int* __restrict__ gcur,
        const int* __restrict__ buckets,
        const float4* __restrict__ posT,
        float4* __restrict__ partials) {
    __shared__ int E[EMAX];        // 17.5 KB staged entries
    __shared__ int S2[EMAX];       // 17.5 KB dst-sorted src ids
    __shared__ int hist[S];        // 4 KB per-node counts (kept for cnt output)
    __shared__ int cur[S];         // 4 KB scatter cursors
    __shared__ int base[S];        // 4 KB exclusive prefix (segment starts)
    const int c = blockIdx.x, p = blockIdx.y, tid = threadIdx.x;
    const int lo = p << S_LOG2;

    for (int i = tid; i < S; i += 512) hist[i] = 0;

    const int len = min(gcur[p], CAP);
    const int beg = (int)((long long)len * c / NC);
    const int end = (int)((long long)len * (c + 1) / NC);
    const int nloc = end - beg;
    const int* __restrict__ bp = buckets + (size_t)p * CAP;

    // stage entries (coalesced global read -> LDS)
    for (int i = tid; i < nloc; i += 512) E[i] = bp[beg + i];
    __syncthreads();

    // per-node histogram
    for (int i = tid; i < nloc; i += 512)
        atomicAdd(&hist[E[i] & (S - 1)], 1);
    __syncthreads();

    // exclusive prefix scan of hist[0..S) by wave 0
    if (tid < 64) {
        int carry = 0;
        for (int b = 0; b < S; b += 64) {
            int v = hist[b + tid];
            int orig = v;
#pragma unroll
            for (int d = 1; d < 64; d <<= 1) {
                int t = __shfl_up(v, d, 64);
                if (tid >= d) v += t;
            }
            int excl = carry + v - orig;
            base[b + tid] = excl;
            cur[b + tid]  = excl;
            carry += __shfl(v, 63, 64);
        }
    }
    __syncthreads();

    // scatter into dst-sorted order (store src id; node implied by segment)
    for (int i = tid; i < nloc; i += 512) {
        int pk = E[i];
        int pos = atomicAdd(&cur[pk & (S - 1)], 1);
        S2[pos] = pk >> S_LOG2;
    }
    __syncthreads();

    // segmented register reduction: thread owns nodes r = tid, tid+512
    float4* __restrict__ outp = partials + ((size_t)(p * NC + c) << S_LOG2);
    for (int r = tid; r < S; r += 512) {
        int nseg = hist[r];
        int node = lo + r;
        float4 b = (node < N_NODES && nseg > 0) ? posT[node]
                                                : make_float4(0.f, 0.f, 0.f, 0.f);
        float ax = 0.f, ay = 0.f, az = 0.f;
        int b0 = base[r];
        for (int j = b0; j < b0 + nseg; ++j) {
            float4 a = posT[S2[j]];
            float px = a.x - b.x, py = a.y - b.y, pz = a.z - b.z;
            float dT = a.w - b.w;
            float w  = dT / (px * px + py * py + pz * pz + EPS);
            ax += w * px; ay += w * py; az += w * pz;
        }
        outp[r] = make_float4(ax, ay, az, (float)nseg);
    }
}

// Sum the NC partials per node, apply mask * DSIGMA_DT / max(cnt,1).
__global__ void finalize_kernel(const float* __restrict__ x,
                                const float4* __restrict__ partials,
                                float* __restrict__ out) {
    int i = blockIdx.x * blockDim.x + threadIdx.x;
    if (i >= N_NODES) return;
    int p = i >> S_LOG2;
    int s = i & (S - 1);
    float ax = 0.f, ay = 0.f, az = 0.f, aw = 0.f;
#pragma unroll
    for (int c = 0; c < NC; ++c) {
        float4 t = partials[(((size_t)(p * NC + c)) << S_LOG2) + s];
        ax += t.x; ay += t.y; az += t.z; aw += t.w;
    }
    float phi = x[i * 9 + 8];
    float cn = aw > 1.0f ? aw : 1.0f;
    float m = (fabsf(phi) < PHI_THRESH) ? (DSIGMA_DT / cn) : 0.0f;
    out[3 * i]     = m * ax;
    out[3 * i + 1] = m * ay;
    out[3 * i + 2] = m * az;
}

// ---------------- fallback: global atomics (small ws) ---------------------
__global__ void prep_kernel(const float* __restrict__ x,
                            const float* __restrict__ pos,
                            float4* __restrict__ posT) {
    int i = blockIdx.x * blockDim.x + threadIdx.x;
    if (i < N_NODES)
        posT[i] = make_float4(pos[3 * i], pos[3 * i + 1], pos[3 * i + 2],
                              x[9 * i + 3]);
}

__global__ void edge_scatter_atomic_kernel(const int* __restrict__ ei,
                                           const float4* __restrict__ posT,
                                           float4* __restrict__ accum) {
    int e = blockIdx.x * blockDim.x + threadIdx.x;
    if (e >= N_EDGES) return;
    int s = ei[e];
    int d = ei[N_EDGES + e];
    float4 a = posT[s];
    float4 b = posT[d];
    float px = a.x - b.x, py = a.y - b.y, pz = a.z - b.z;
    float dT = a.w - b.w;
    float w  = dT / (px * px + py * py + pz * pz + EPS);
    float* ac = (float*)&accum[d];
    atomicAdd(ac,     w * px);
    atomicAdd(ac + 1, w * py);
    atomicAdd(ac + 2, w * pz);
    atomicAdd(ac + 3, 1.0f);
}

__global__ void finalize_accum_kernel(const float* __restrict__ x,
                                      const float4* __restrict__ accum,
                                      float* __restrict__ out) {
    int i = blockIdx.x * blockDim.x + threadIdx.x;
    if (i >= N_NODES) return;
    float4 a = accum[i];
    float phi = x[i * 9 + 8];
    float cn = a.w > 1.0f ? a.w : 1.0f;
    float m = (fabsf(phi) < PHI_THRESH) ? (DSIGMA_DT / cn) : 0.0f;
    out[3 * i]     = m * a.x;
    out[3 * i + 1] = m * a.y;
    out[3 * i + 2] = m * a.z;
}

extern "C" void kernel_launch(void* const* d_in, const int* in_sizes, int n_in,
                              void* d_out, int out_size, void* d_ws, size_t ws_size,
                              hipStream_t stream) {
    const float* x   = (const float*)d_in[0];
    const float* pos = (const float*)d_in[1];
    const int*   ei  = (const int*)d_in[2];
    float* out = (float*)d_out;

    // ws layout: [posT][partials][gcur pad 512B][buckets]
    const size_t posT_b = (size_t)N_NODES * sizeof(float4);          // 1.6 MB
    const size_t part_b = (size_t)NC * NPART * S * sizeof(float4);   // 12.8 MB
    const size_t gcur_b = 512;
    const size_t buck_b = (size_t)NPART * CAP * sizeof(int);         // 13.7 MB

    char* w = (char*)d_ws;
    float4* posT     = (float4*)w;
    float4* partials = (float4*)(w + posT_b);
    int*    gcur     = (int*)(w + posT_b + part_b);
    int*    buckets  = (int*)(w + posT_b + part_b + gcur_b);

    const size_t need_full = posT_b + part_b + gcur_b + buck_b;      // ~28.2 MB

    const int B = 256;

    if (ws_size >= need_full) {
        hipMemsetAsync(gcur, 0, gcur_b, stream);
        bin_kernel<<<NB, 512, 0, stream>>>((const int4*)ei, x, pos, posT, gcur, buckets);
        dim3 grid(NC, NPART);
        part_kernel<<<grid, 512, 0, stream>>>(gcur, buckets, posT, partials);
        finalize_kernel<<<(N_NODES + B - 1) / B, B, 0, stream>>>(x, partials, out);
    } else {
        float4* accum = (float4*)(w + posT_b);  // 1.6 MB
        prep_kernel<<<(N_NODES + B - 1) / B, B, 0, stream>>>(x, pos, posT);
        hipMemsetAsync(accum, 0, (size_t)N_NODES * sizeof(float4), stream);
        edge_scatter_atomic_kernel<<<(N_EDGES + B - 1) / B, B, 0, stream>>>(ei, posT, accum);
        finalize_accum_kernel<<<(N_NODES + B - 1) / B, B, 0, stream>>>(x, accum, out);
    }
}